// Round 7
// baseline (360.240 us; speedup 1.0000x reference)
//
#include <hip/hip_runtime.h>

// Conv: out = (norm * (x + segment_sum(x[sources], targets))) @ W
// N = 100000, E = 4000000, C = 64, fp32.
// Pipeline: prep (fused x->bf16 cvt + bucket hist) -> tiny scan -> bin v2
// (8K chunks, on-the-fly records, dense runs) -> fused per-bucket sort
// (coalesced csr write) -> bf16 transposed gather (64 edges in flight/wave)
// + fused scale+matmul.

constexpr int C = 64;
constexpr int BN = 128;      // nodes per bucket
constexpr int CHUNK2 = 8192; // edges per hist/bin block (512 threads)
constexpr int MAXB = 1024;   // LDS bucket-hist capacity (NB = 782)
constexpr int CAP = 6144;    // LDS sort staging (max bucket edges; avg 5120)

// --- 1. fused: x -> bf16 (RNE)  +  bucket histogram -------------------------
__global__ __launch_bounds__(512) void prep_kernel(
    const float* __restrict__ x, unsigned* __restrict__ xb,
    const int* __restrict__ tgt, int* __restrict__ bhist,
    int E, int NB, int histBlocks, int total8) {
  __shared__ int h[MAXB];
  if ((int)blockIdx.x < histBlocks) {
    for (int i = threadIdx.x; i < NB; i += 512) h[i] = 0;
    __syncthreads();
    int base = blockIdx.x * CHUNK2;
    int end = base + CHUNK2; if (end > E) end = E;
    for (int i = base + threadIdx.x; i < end; i += 512)
      atomicAdd(&h[tgt[i] >> 7], 1);
    __syncthreads();
    for (int i = threadIdx.x; i < NB; i += 512)
      if (h[i]) atomicAdd(&bhist[i], h[i]);
  } else {
    int i = (blockIdx.x - histBlocks) * 512 + threadIdx.x;
    if (i < total8) {
      const float4* x4 = (const float4*)x;
      float4 a = x4[i * 2], bq = x4[i * 2 + 1];
      float f[8] = {a.x, a.y, a.z, a.w, bq.x, bq.y, bq.z, bq.w};
      unsigned w[4];
#pragma unroll
      for (int k = 0; k < 4; k++) {
        unsigned u0 = __float_as_uint(f[2 * k]);
        unsigned u1 = __float_as_uint(f[2 * k + 1]);
        u0 = (u0 + 0x7FFFu + ((u0 >> 16) & 1u)) >> 16;
        u1 = (u1 + 0x7FFFu + ((u1 >> 16) & 1u)) >> 16;
        w[k] = u0 | (u1 << 16);
      }
      ((uint4*)xb)[i] = make_uint4(w[0], w[1], w[2], w[3]);
    }
  }
}

// --- 2. scan of NB bucket counts (1 block); also offsets[N] = E -------------
__global__ __launch_bounds__(256) void bscan_kernel(
    const int* __restrict__ bhist, int* __restrict__ bbase,
    int* __restrict__ cursor, int* __restrict__ offsets, int NB, int N, int E) {
  __shared__ int partials[256];
  int tid = threadIdx.x;
  int per = (NB + 255) / 256;
  int lo = tid * per, hi = lo + per;
  if (lo > NB) lo = NB;
  if (hi > NB) hi = NB;
  int s = 0;
  for (int i = lo; i < hi; i++) s += bhist[i];
  partials[tid] = s;
  __syncthreads();
  for (int off = 1; off < 256; off <<= 1) {
    int v = partials[tid];
    int a = (tid >= off) ? partials[tid - off] : 0;
    __syncthreads();
    partials[tid] = v + a;
    __syncthreads();
  }
  int run = partials[tid] - s;
  for (int i = lo; i < hi; i++) { bbase[i] = run; cursor[i] = run; run += bhist[i]; }
  if (tid == 255) bbase[NB] = partials[255];
  if (tid == 0) offsets[N] = E;
}

// --- 3. bin v2: 8K chunks, on-the-fly records, dense runs -------------------
// No rec/bkt LDS staging: placement pass re-reads tgt/src (L1/L2-hot).
// Run length ~10.5 recs (42 B) halves scattered-write line amplification.
__global__ __launch_bounds__(512) void bin_kernel(
    const int* __restrict__ src, const int* __restrict__ tgt,
    int* __restrict__ gcursor, unsigned* __restrict__ recs, int E, int NB) {
  __shared__ int hist[MAXB];
  __shared__ int gb[MAXB];
  __shared__ int cur[MAXB];
  int tid = threadIdx.x;
  int base = blockIdx.x * CHUNK2;
  int count = E - base; if (count > CHUNK2) count = CHUNK2;

  for (int i = tid; i < NB; i += 512) hist[i] = 0;
  __syncthreads();
  for (int i = tid; i < count; i += 512)
    atomicAdd(&hist[tgt[base + i] >> 7], 1);
  __syncthreads();
  for (int i = tid; i < NB; i += 512) {
    int c = hist[i];
    gb[i] = c ? atomicAdd(&gcursor[i], c) : 0;
    cur[i] = 0;
  }
  __syncthreads();
  for (int i = tid; i < count; i += 512) {
    int t = tgt[base + i];
    int s = src[base + i];
    int b = t >> 7;
    int idx = atomicAdd(&cur[b], 1);
    recs[gb[b] + idx] = ((unsigned)s << 7) | (unsigned)(t & 127);
  }
}

// --- 4. fused per-bucket sort: per-node offsets + coalesced csr write -------
__global__ __launch_bounds__(256) void sortoff_kernel(
    const unsigned* __restrict__ recs, const int* __restrict__ bbase,
    int* __restrict__ csr_src, int* __restrict__ offsets, int N) {
  __shared__ int cnt[BN];
  __shared__ int pre[BN];
  __shared__ int sorted[CAP];  // 24 KB staging -> coalesced global write
  int tid = threadIdx.x;
  int b = blockIdx.x;
  int n0 = b * BN;
  int nn = N - n0; if (nn > BN) nn = BN;
  int beg = bbase[b], end = bbase[b + 1];
  int m = end - beg;

  if (tid < BN) cnt[tid] = 0;
  __syncthreads();
  for (int r = beg + tid; r < end; r += 256)
    atomicAdd(&cnt[recs[r] & 127u], 1);
  __syncthreads();
  if (tid < BN) pre[tid] = cnt[tid];
  __syncthreads();
  for (int off = 1; off < BN; off <<= 1) {
    int v = (tid < BN) ? pre[tid] : 0;
    int a = (tid >= off && tid < BN) ? pre[tid - off] : 0;
    __syncthreads();
    if (tid < BN) pre[tid] = v + a;
    __syncthreads();
  }
  if (tid < nn) offsets[n0 + tid] = beg + pre[tid] - cnt[tid];
  if (tid < BN) cnt[tid] = pre[tid] - cnt[tid];  // bucket-local cursor
  __syncthreads();

  if (m <= CAP) {
    for (int r = beg + tid; r < end; r += 256) {
      unsigned rc = recs[r];
      int p = atomicAdd(&cnt[rc & 127u], 1);
      sorted[p] = (int)(rc >> 7);
    }
    __syncthreads();
    for (int i = tid; i < m; i += 256) csr_src[beg + i] = sorted[i];
  } else {  // safety fallback
    for (int r = beg + tid; r < end; r += 256) {
      unsigned rc = recs[r];
      int p = atomicAdd(&cnt[rc & 127u], 1);
      csr_src[beg + p] = (int)(rc >> 7);
    }
  }
}

// --- 5a. bf16 transposed gather: 64 edges in flight per wave ----------------
// Wave = 8 lanes (uint4 = 8 bf16 channels) x 8 edge slots, unroll 8.
__global__ __launch_bounds__(256) void gather_bf16_kernel(
    const float* __restrict__ x, const unsigned* __restrict__ xb,
    const int* __restrict__ offsets, const int* __restrict__ csr_src,
    const float* __restrict__ norm, const float* __restrict__ W,
    float* __restrict__ out, int N) {
  int tid = threadIdx.x;
  int lane = tid & 63;
  int wave = tid >> 6;
  int sub = lane & 7;   // channels 8*sub .. 8*sub+7
  int grp = lane >> 3;  // edge slot 0..7

  float wreg[C];
#pragma unroll
  for (int k = 0; k < C; k++) wreg[k] = W[k * C + lane];

  const float4* x4 = (const float4*)x;
  const uint4* xb4 = (const uint4*)xb;  // row = 8 uint4
  int gw = blockIdx.x * 4 + wave;
  int nwaves = gridDim.x * 4;

  for (int n = gw; n < N; n += nwaves) {
    int beg = offsets[n], end = offsets[n + 1];
    float acc[8];
    if (grp == 0) {  // exact fp32 self term
      float4 a = x4[n * 16 + sub * 2], bq = x4[n * 16 + sub * 2 + 1];
      acc[0] = a.x; acc[1] = a.y; acc[2] = a.z; acc[3] = a.w;
      acc[4] = bq.x; acc[5] = bq.y; acc[6] = bq.z; acc[7] = bq.w;
    } else {
#pragma unroll
      for (int j = 0; j < 8; j++) acc[j] = 0.0f;
    }

    for (int e0 = beg; e0 < end; e0 += 64) {  // 64 edges in flight/wave
#pragma unroll
      for (int u = 0; u < 8; u++) {
        int e = e0 + 8 * u + grp;
        if (e < end) {
          int s = csr_src[e];
          uint4 v = xb4[s * 8 + sub];  // 128B row per 8-lane group
          acc[0] += __uint_as_float(v.x << 16);
          acc[1] += __uint_as_float(v.x & 0xFFFF0000u);
          acc[2] += __uint_as_float(v.y << 16);
          acc[3] += __uint_as_float(v.y & 0xFFFF0000u);
          acc[4] += __uint_as_float(v.z << 16);
          acc[5] += __uint_as_float(v.z & 0xFFFF0000u);
          acc[6] += __uint_as_float(v.w << 16);
          acc[7] += __uint_as_float(v.w & 0xFFFF0000u);
        }
      }
    }

#pragma unroll
    for (int j = 0; j < 8; j++) {
      acc[j] += __shfl_xor(acc[j], 8, 64);
      acc[j] += __shfl_xor(acc[j], 16, 64);
      acc[j] += __shfl_xor(acc[j], 32, 64);
    }

    float nv = norm[n];
#pragma unroll
    for (int j = 0; j < 8; j++) acc[j] *= nv;

    float o = 0.0f;
#pragma unroll
    for (int s = 0; s < 8; s++) {
#pragma unroll
      for (int j = 0; j < 8; j++) {
        o = fmaf(__shfl(acc[j], s, 64), wreg[8 * s + j], o);
      }
    }
    out[n * C + lane] = o;
  }
}

// --- 5b. fp32 fallback gather (R5, proven) ----------------------------------
__global__ __launch_bounds__(256) void gather_f32_kernel(
    const float* __restrict__ x, const int* __restrict__ offsets,
    const int* __restrict__ csr_src, const float* __restrict__ norm,
    const float* __restrict__ W, float* __restrict__ out, int N) {
  int tid = threadIdx.x;
  int lane = tid & 63;
  int wave = tid >> 6;
  int sub = lane & 15;
  int grp = lane >> 4;
  float wreg[C];
#pragma unroll
  for (int k = 0; k < C; k++) wreg[k] = W[k * C + lane];
  const float4* x4 = (const float4*)x;
  int gw = blockIdx.x * 4 + wave;
  int nwaves = gridDim.x * 4;
  for (int n = gw; n < N; n += nwaves) {
    int beg = offsets[n], end = offsets[n + 1];
    float4 acc;
    if (grp == 0) acc = x4[n * 16 + sub];
    else { acc.x = 0.f; acc.y = 0.f; acc.z = 0.f; acc.w = 0.f; }
    for (int e0 = beg; e0 < end; e0 += 16) {
#pragma unroll
      for (int u = 0; u < 4; u++) {
        int e = e0 + 4 * u + grp;
        if (e < end) {
          int s = csr_src[e];
          float4 v = x4[s * 16 + sub];
          acc.x += v.x; acc.y += v.y; acc.z += v.z; acc.w += v.w;
        }
      }
    }
    acc.x += __shfl_xor(acc.x, 16, 64); acc.y += __shfl_xor(acc.y, 16, 64);
    acc.z += __shfl_xor(acc.z, 16, 64); acc.w += __shfl_xor(acc.w, 16, 64);
    acc.x += __shfl_xor(acc.x, 32, 64); acc.y += __shfl_xor(acc.y, 32, 64);
    acc.z += __shfl_xor(acc.z, 32, 64); acc.w += __shfl_xor(acc.w, 32, 64);
    float nv = norm[n];
    acc.x *= nv; acc.y *= nv; acc.z *= nv; acc.w *= nv;
    float o = 0.0f;
#pragma unroll
    for (int k16 = 0; k16 < 16; k16++) {
      o = fmaf(__shfl(acc.x, k16, 64), wreg[4 * k16 + 0], o);
      o = fmaf(__shfl(acc.y, k16, 64), wreg[4 * k16 + 1], o);
      o = fmaf(__shfl(acc.z, k16, 64), wreg[4 * k16 + 2], o);
      o = fmaf(__shfl(acc.w, k16, 64), wreg[4 * k16 + 3], o);
    }
    out[n * C + lane] = o;
  }
}

extern "C" void kernel_launch(void* const* d_in, const int* in_sizes, int n_in,
                              void* d_out, int out_size, void* d_ws, size_t ws_size,
                              hipStream_t stream) {
  const float* x       = (const float*)d_in[0];
  const int*   sources = (const int*)d_in[1];
  const int*   targets = (const int*)d_in[2];
  const float* norm    = (const float*)d_in[3];
  const float* weight  = (const float*)d_in[4];
  float* out = (float*)d_out;

  int N = in_sizes[0] / C;     // 100000
  int E = in_sizes[1];         // 4000000
  int NB = (N + BN - 1) / BN;  // 782

  // ws: bhist[NB] | bbase[NB+1] | cursor[NB] | offsets[N+1] | csr_src[E] | xb
  int* bhist   = (int*)d_ws;
  int* bbase   = bhist + NB;
  int* cursor  = bbase + (NB + 1);
  int* offsets = cursor + NB;
  int* csr_src = offsets + (N + 1);
  unsigned* xb = (unsigned*)(csr_src + E);
  // recs (16 MB) lives in d_out; fully written by bin, dead after sortoff.
  unsigned* recs = (unsigned*)out;

  size_t need_bf16 = (size_t)(3 * NB + 1 + N + 1 + E) * 4 + (size_t)N * C * 2;
  bool use_bf16 = ws_size >= need_bf16;

  hipMemsetAsync(bhist, 0, (size_t)NB * sizeof(int), stream);

  int eb = (E + CHUNK2 - 1) / CHUNK2;  // 489
  int total8 = N * C / 8;              // 800000
  int cvtBlocks = use_bf16 ? (total8 + 511) / 512 : 0;
  prep_kernel<<<eb + cvtBlocks, 512, 0, stream>>>(x, xb, targets, bhist, E, NB, eb, total8);
  bscan_kernel<<<1, 256, 0, stream>>>(bhist, bbase, cursor, offsets, NB, N, E);
  bin_kernel<<<eb, 512, 0, stream>>>(sources, targets, cursor, recs, E, NB);
  sortoff_kernel<<<NB, 256, 0, stream>>>(recs, bbase, csr_src, offsets, N);
  if (use_bf16) {
    gather_bf16_kernel<<<4096, 256, 0, stream>>>(x, xb, offsets, csr_src, norm, weight, out, N);
  } else {
    gather_f32_kernel<<<4096, 256, 0, stream>>>(x, offsets, csr_src, norm, weight, out, N);
  }
}

// Round 8
// 330.034 us; speedup vs baseline: 1.0915x; 1.0915x over previous
//
#include <hip/hip_runtime.h>

// Conv: out = (norm * (x + segment_sum(x[sources], targets))) @ W
// N = 100000, E = 4000000, C = 64, fp32.
// Pipeline: prep (fused x->bf16 cvt + bucket hist) -> tiny scan -> bin
// (dense-run bucket sort of edge records into ws) -> sortgather (per-bucket
// LDS counting sort + bf16 transposed gather + fused scale+matmul).

constexpr int C = 64;
constexpr int BN = 128;      // nodes per bucket
constexpr int CHUNK = 4096;  // edges per bin block (256 threads)
constexpr int CHUNK2 = 8192; // edges per hist block (512 threads)
constexpr int MAXB = 1024;   // LDS bucket-hist capacity (NB = 782)
constexpr int CAP = 6144;    // LDS sort staging (bucket max ~5400 @ 14 sigma)

// --- 1. fused: x -> bf16 (RNE)  +  bucket histogram -------------------------
__global__ __launch_bounds__(512) void prep_kernel(
    const float* __restrict__ x, unsigned* __restrict__ xb,
    const int* __restrict__ tgt, int* __restrict__ bhist,
    int E, int NB, int histBlocks, int total8) {
  __shared__ int h[MAXB];
  if ((int)blockIdx.x < histBlocks) {
    for (int i = threadIdx.x; i < NB; i += 512) h[i] = 0;
    __syncthreads();
    int base = blockIdx.x * CHUNK2;
    int end = base + CHUNK2; if (end > E) end = E;
    for (int i = base + threadIdx.x; i < end; i += 512)
      atomicAdd(&h[tgt[i] >> 7], 1);
    __syncthreads();
    for (int i = threadIdx.x; i < NB; i += 512)
      if (h[i]) atomicAdd(&bhist[i], h[i]);
  } else {
    int i = (blockIdx.x - histBlocks) * 512 + threadIdx.x;
    if (i < total8) {
      const float4* x4 = (const float4*)x;
      float4 a = x4[i * 2], bq = x4[i * 2 + 1];
      float f[8] = {a.x, a.y, a.z, a.w, bq.x, bq.y, bq.z, bq.w};
      unsigned w[4];
#pragma unroll
      for (int k = 0; k < 4; k++) {
        unsigned u0 = __float_as_uint(f[2 * k]);
        unsigned u1 = __float_as_uint(f[2 * k + 1]);
        u0 = (u0 + 0x7FFFu + ((u0 >> 16) & 1u)) >> 16;
        u1 = (u1 + 0x7FFFu + ((u1 >> 16) & 1u)) >> 16;
        w[k] = u0 | (u1 << 16);
      }
      ((uint4*)xb)[i] = make_uint4(w[0], w[1], w[2], w[3]);
    }
  }
}

// --- 2. scan of NB bucket counts (1 block) ----------------------------------
__global__ __launch_bounds__(256) void bscan_kernel(
    const int* __restrict__ bhist, int* __restrict__ bbase,
    int* __restrict__ cursor, int NB) {
  __shared__ int partials[256];
  int tid = threadIdx.x;
  int per = (NB + 255) / 256;
  int lo = tid * per, hi = lo + per;
  if (lo > NB) lo = NB;
  if (hi > NB) hi = NB;
  int s = 0;
  for (int i = lo; i < hi; i++) s += bhist[i];
  partials[tid] = s;
  __syncthreads();
  for (int off = 1; off < 256; off <<= 1) {
    int v = partials[tid];
    int a = (tid >= off) ? partials[tid - off] : 0;
    __syncthreads();
    partials[tid] = v + a;
    __syncthreads();
  }
  int run = partials[tid] - s;
  for (int i = lo; i < hi; i++) { bbase[i] = run; cursor[i] = run; run += bhist[i]; }
  if (tid == 255) bbase[NB] = partials[255];
}

// --- 3. bin (R6 v1): dense per-(block,bucket) runs into recs ----------------
__global__ __launch_bounds__(256) void bin_kernel(
    const int* __restrict__ src, const int* __restrict__ tgt,
    int* __restrict__ gcursor, unsigned* __restrict__ recs, int E, int NB) {
  __shared__ unsigned rec[CHUNK];
  __shared__ int bkt[CHUNK];
  __shared__ int hist[MAXB];
  __shared__ int gb[MAXB];
  int tid = threadIdx.x;
  int base = blockIdx.x * CHUNK;
  int count = E - base; if (count > CHUNK) count = CHUNK;

  for (int i = tid; i < NB; i += 256) hist[i] = 0;
  __syncthreads();
  for (int i = tid; i < count; i += 256) {
    int s = src[base + i], t = tgt[base + i];
    int b = t >> 7;
    rec[i] = ((unsigned)s << 7) | (unsigned)(t & 127);
    bkt[i] = b;
    atomicAdd(&hist[b], 1);
  }
  __syncthreads();
  for (int i = tid; i < NB; i += 256) {
    int c = hist[i];
    gb[i] = c ? atomicAdd(&gcursor[i], c) : 0;
  }
  __syncthreads();
  for (int i = tid; i < NB; i += 256) hist[i] = 0;
  __syncthreads();
  for (int i = tid; i < count; i += 256) {
    int b = bkt[i];
    int idx = atomicAdd(&hist[b], 1);
    recs[gb[b] + idx] = rec[i];
  }
}

// --- 4. fused sort + gather + scale + matmul --------------------------------
// One block per bucket: LDS counting sort of the bucket's recs (per-node
// starts in nstart[]), then transposed gather from the LDS-sorted src list.
// USE_BF16: 8 lanes (uint4 = 8 bf16 ch) x 8 slots; else 16 lanes (float4) x 4.
template <bool USE_BF16>
__global__ __launch_bounds__(256) void sortgather_kernel(
    const float* __restrict__ x, const unsigned* __restrict__ xb,
    const unsigned* __restrict__ recs, const int* __restrict__ bbase,
    const float* __restrict__ norm, const float* __restrict__ W,
    float* __restrict__ out, int N) {
  __shared__ int cnt[BN];
  __shared__ int pre[BN];
  __shared__ int nstart[BN + 1];
  __shared__ int sorted[CAP];  // 24 KB
  int tid = threadIdx.x;
  int lane = tid & 63;
  int wave = tid >> 6;
  int b = blockIdx.x;
  int n0 = b * BN;
  int nn = N - n0; if (nn > BN) nn = BN;
  int beg = bbase[b], end = bbase[b + 1];
  int m = end - beg;

  float wreg[C];
#pragma unroll
  for (int k = 0; k < C; k++) wreg[k] = W[k * C + lane];

  // counting sort into LDS
  if (tid < BN) cnt[tid] = 0;
  __syncthreads();
  for (int r = beg + tid; r < end; r += 256)
    atomicAdd(&cnt[recs[r] & 127u], 1);
  __syncthreads();
  if (tid < BN) pre[tid] = cnt[tid];
  __syncthreads();
  for (int off = 1; off < BN; off <<= 1) {
    int v = 0, a = 0;
    if (tid < BN) { v = pre[tid]; a = (tid >= off) ? pre[tid - off] : 0; }
    __syncthreads();
    if (tid < BN) pre[tid] = v + a;
    __syncthreads();
  }
  if (tid < BN) {
    nstart[tid] = pre[tid] - cnt[tid];  // exclusive prefix
    cnt[tid] = pre[tid] - cnt[tid];     // bucket-local cursor
  }
  if (tid == 0) nstart[BN] = m;
  __syncthreads();
  bool fits = (m <= CAP);
  if (fits) {
    for (int r = beg + tid; r < end; r += 256) {
      unsigned rc = recs[r];
      int p = atomicAdd(&cnt[rc & 127u], 1);
      sorted[p] = (int)(rc >> 7);
    }
  }
  __syncthreads();

  int sub, grp;
  if (USE_BF16) { sub = lane & 7;  grp = lane >> 3; }
  else          { sub = lane & 15; grp = lane >> 4; }
  const float4* x4 = (const float4*)x;
  const uint4* xb4 = (const uint4*)xb;  // bf16 row = 8 uint4

  for (int i = wave; i < nn; i += 4) {
    int n = n0 + i;
    float acc[8];
    if (grp == 0) {  // exact fp32 self term
      if (USE_BF16) {
        float4 a = x4[n * 16 + sub * 2], bq = x4[n * 16 + sub * 2 + 1];
        acc[0] = a.x; acc[1] = a.y; acc[2] = a.z; acc[3] = a.w;
        acc[4] = bq.x; acc[5] = bq.y; acc[6] = bq.z; acc[7] = bq.w;
      } else {
        float4 a = x4[n * 16 + sub];
        acc[0] = a.x; acc[1] = a.y; acc[2] = a.z; acc[3] = a.w;
        acc[4] = acc[5] = acc[6] = acc[7] = 0.0f;
      }
    } else {
#pragma unroll
      for (int j = 0; j < 8; j++) acc[j] = 0.0f;
    }

    if (fits) {
      int gbeg = nstart[i], gend = nstart[i + 1];
      if (USE_BF16) {
        for (int e0 = gbeg; e0 < gend; e0 += 64) {
#pragma unroll
          for (int u = 0; u < 8; u++) {
            int e = e0 + 8 * u + grp;
            if (e < gend) {
              int s = sorted[e];
              uint4 v = xb4[s * 8 + sub];
              acc[0] += __uint_as_float(v.x << 16);
              acc[1] += __uint_as_float(v.x & 0xFFFF0000u);
              acc[2] += __uint_as_float(v.y << 16);
              acc[3] += __uint_as_float(v.y & 0xFFFF0000u);
              acc[4] += __uint_as_float(v.z << 16);
              acc[5] += __uint_as_float(v.z & 0xFFFF0000u);
              acc[6] += __uint_as_float(v.w << 16);
              acc[7] += __uint_as_float(v.w & 0xFFFF0000u);
            }
          }
        }
      } else {
        for (int e0 = gbeg; e0 < gend; e0 += 16) {
#pragma unroll
          for (int u = 0; u < 4; u++) {
            int e = e0 + 4 * u + grp;
            if (e < gend) {
              int s = sorted[e];
              float4 v = x4[s * 16 + sub];
              acc[0] += v.x; acc[1] += v.y; acc[2] += v.z; acc[3] += v.w;
            }
          }
        }
      }
    } else {  // overflow fallback (statistically unreachable): filtered scan
      int step = USE_BF16 ? 8 : 4;
      for (int r0 = beg; r0 < end; r0 += step) {
        int e = r0 + grp;
        if (e < end) {
          unsigned rc = recs[e];
          if ((int)(rc & 127u) == i) {
            int s = (int)(rc >> 7);
            if (USE_BF16) {
              uint4 v = xb4[s * 8 + sub];
              acc[0] += __uint_as_float(v.x << 16);
              acc[1] += __uint_as_float(v.x & 0xFFFF0000u);
              acc[2] += __uint_as_float(v.y << 16);
              acc[3] += __uint_as_float(v.y & 0xFFFF0000u);
              acc[4] += __uint_as_float(v.z << 16);
              acc[5] += __uint_as_float(v.z & 0xFFFF0000u);
              acc[6] += __uint_as_float(v.w << 16);
              acc[7] += __uint_as_float(v.w & 0xFFFF0000u);
            } else {
              float4 v = x4[s * 16 + sub];
              acc[0] += v.x; acc[1] += v.y; acc[2] += v.z; acc[3] += v.w;
            }
          }
        }
      }
    }

    // reduce edge slots
    if (USE_BF16) {
#pragma unroll
      for (int j = 0; j < 8; j++) {
        acc[j] += __shfl_xor(acc[j], 8, 64);
        acc[j] += __shfl_xor(acc[j], 16, 64);
        acc[j] += __shfl_xor(acc[j], 32, 64);
      }
    } else {
#pragma unroll
      for (int j = 0; j < 4; j++) {
        acc[j] += __shfl_xor(acc[j], 16, 64);
        acc[j] += __shfl_xor(acc[j], 32, 64);
      }
    }

    float nv = norm[n];
    float o = 0.0f;
    if (USE_BF16) {
#pragma unroll
      for (int j = 0; j < 8; j++) acc[j] *= nv;
#pragma unroll
      for (int s = 0; s < 8; s++)
#pragma unroll
        for (int j = 0; j < 8; j++)
          o = fmaf(__shfl(acc[j], s, 64), wreg[8 * s + j], o);
    } else {
#pragma unroll
      for (int j = 0; j < 4; j++) acc[j] *= nv;
#pragma unroll
      for (int s = 0; s < 16; s++)
#pragma unroll
        for (int j = 0; j < 4; j++)
          o = fmaf(__shfl(acc[j], s, 64), wreg[4 * s + j], o);
    }
    out[n * C + lane] = o;
  }
}

extern "C" void kernel_launch(void* const* d_in, const int* in_sizes, int n_in,
                              void* d_out, int out_size, void* d_ws, size_t ws_size,
                              hipStream_t stream) {
  const float* x       = (const float*)d_in[0];
  const int*   sources = (const int*)d_in[1];
  const int*   targets = (const int*)d_in[2];
  const float* norm    = (const float*)d_in[3];
  const float* weight  = (const float*)d_in[4];
  float* out = (float*)d_out;

  int N = in_sizes[0] / C;     // 100000
  int E = in_sizes[1];         // 4000000
  int NB = (N + BN - 1) / BN;  // 782

  // need (bf16): xb 12.8MB + (3NB+1+E)*4 = 16.0MB  => 28.8MB (proven fits)
  size_t xb_words = (size_t)N * C / 2;  // 16-bit vals packed in unsigned
  size_t meta_words = (size_t)3 * NB + 1 + (size_t)E;
  bool use_bf16 = ws_size >= (xb_words + meta_words) * 4;

  unsigned* xb; int* bhist;
  if (use_bf16) {
    xb = (unsigned*)d_ws;                 // 16B-aligned (12.8MB block first)
    bhist = (int*)d_ws + xb_words;
  } else {
    xb = nullptr;
    bhist = (int*)d_ws;
  }
  int* bbase  = bhist + NB;
  int* cursor = bbase + (NB + 1);
  unsigned* recs = (unsigned*)(cursor + NB);

  hipMemsetAsync(bhist, 0, (size_t)NB * sizeof(int), stream);

  int hb = (E + CHUNK2 - 1) / CHUNK2;  // 489
  int total8 = N * C / 8;              // 800000
  int cvtBlocks = use_bf16 ? (total8 + 511) / 512 : 0;
  prep_kernel<<<hb + cvtBlocks, 512, 0, stream>>>(x, xb, targets, bhist, E, NB, hb, total8);
  bscan_kernel<<<1, 256, 0, stream>>>(bhist, bbase, cursor, NB);
  bin_kernel<<<(E + CHUNK - 1) / CHUNK, 256, 0, stream>>>(sources, targets, cursor, recs, E, NB);
  if (use_bf16) {
    sortgather_kernel<true><<<NB, 256, 0, stream>>>(x, xb, recs, bbase, norm, weight, out, N);
  } else {
    sortgather_kernel<false><<<NB, 256, 0, stream>>>(x, xb, recs, bbase, norm, weight, out, N);
  }
}

// Round 10
// 310.483 us; speedup vs baseline: 1.1603x; 1.0630x over previous
//
#include <hip/hip_runtime.h>

// Conv: out = (norm * (x + segment_sum(x[sources], targets))) @ W
// N = 100000, E = 4000000, C = 64, fp32.
// Pipeline: prep (fused x->bf16 cvt + bucket hist) -> tiny scan -> bin v3
// (8K-chunk LDS-staged dense-run bucket sort) -> sortgather (per-bucket LDS
// counting sort + bf16 transposed gather + fused scale+matmul).
// NOTE: fp8 gather tried in R9 -> absmax 0.875 > 0.65 threshold. bf16 is the
// floor precision (absmax 0.125, 5x margin). Self term exact fp32.

constexpr int C = 64;
constexpr int BN = 128;       // nodes per bucket
constexpr int CHUNK2 = 8192;  // edges per hist/bin block (512 threads)
constexpr int MAXB = 1024;    // LDS bucket arrays capacity (NB = 782)
constexpr int CAP = 6144;     // LDS sort staging (bucket avg 5120, max ~5400)

// --- 1. fused: x -> bf16 (RNE)  +  bucket histogram -------------------------
__global__ __launch_bounds__(512) void prep_kernel(
    const float* __restrict__ x, unsigned* __restrict__ xb,
    const int* __restrict__ tgt, int* __restrict__ bhist,
    int E, int NB, int histBlocks, int total8) {
  __shared__ int h[MAXB];
  if ((int)blockIdx.x < histBlocks) {
    for (int i = threadIdx.x; i < NB; i += 512) h[i] = 0;
    __syncthreads();
    int base = blockIdx.x * CHUNK2;
    int end = base + CHUNK2; if (end > E) end = E;
    for (int i = base + threadIdx.x; i < end; i += 512)
      atomicAdd(&h[tgt[i] >> 7], 1);
    __syncthreads();
    for (int i = threadIdx.x; i < NB; i += 512)
      if (h[i]) atomicAdd(&bhist[i], h[i]);
  } else {
    int i = (blockIdx.x - histBlocks) * 512 + threadIdx.x;  // 8 floats each
    if (i < total8) {
      const float4* x4 = (const float4*)x;
      float4 a = x4[i * 2], bq = x4[i * 2 + 1];
      float f[8] = {a.x, a.y, a.z, a.w, bq.x, bq.y, bq.z, bq.w};
      unsigned w[4];
#pragma unroll
      for (int k = 0; k < 4; k++) {
        unsigned u0 = __float_as_uint(f[2 * k]);
        unsigned u1 = __float_as_uint(f[2 * k + 1]);
        u0 = (u0 + 0x7FFFu + ((u0 >> 16) & 1u)) >> 16;
        u1 = (u1 + 0x7FFFu + ((u1 >> 16) & 1u)) >> 16;
        w[k] = u0 | (u1 << 16);
      }
      ((uint4*)xb)[i] = make_uint4(w[0], w[1], w[2], w[3]);
    }
  }
}

// --- 2. scan of NB bucket counts (1 block) ----------------------------------
__global__ __launch_bounds__(256) void bscan_kernel(
    const int* __restrict__ bhist, int* __restrict__ bbase,
    int* __restrict__ cursor, int NB) {
  __shared__ int partials[256];
  int tid = threadIdx.x;
  int per = (NB + 255) / 256;
  int lo = tid * per, hi = lo + per;
  if (lo > NB) lo = NB;
  if (hi > NB) hi = NB;
  int s = 0;
  for (int i = lo; i < hi; i++) s += bhist[i];
  partials[tid] = s;
  __syncthreads();
  for (int off = 1; off < 256; off <<= 1) {
    int v = partials[tid];
    int a = (tid >= off) ? partials[tid - off] : 0;
    __syncthreads();
    partials[tid] = v + a;
    __syncthreads();
  }
  int run = partials[tid] - s;
  for (int i = lo; i < hi; i++) { bbase[i] = run; cursor[i] = run; run += bhist[i]; }
  if (tid == 255) bbase[NB] = partials[255];
}

// --- 3. bin v3: 8K chunks, LDS staging, dense ~10.5-rec runs ----------------
__global__ __launch_bounds__(512) void bin_kernel(
    const int* __restrict__ src, const int* __restrict__ tgt,
    int* __restrict__ gcursor, unsigned* __restrict__ recs, int E, int NB) {
  __shared__ unsigned rec[CHUNK2];        // 32 KB
  __shared__ unsigned short bkt[CHUNK2];  // 16 KB
  __shared__ int hist[MAXB];              // 4 KB
  __shared__ int gb[MAXB];                // 4 KB
  int tid = threadIdx.x;
  int base = blockIdx.x * CHUNK2;
  int count = E - base; if (count > CHUNK2) count = CHUNK2;

  for (int i = tid; i < NB; i += 512) hist[i] = 0;
  __syncthreads();
  for (int i = tid; i < count; i += 512) {
    int s = src[base + i], t = tgt[base + i];
    int b = t >> 7;
    rec[i] = ((unsigned)s << 7) | (unsigned)(t & 127);
    bkt[i] = (unsigned short)b;
    atomicAdd(&hist[b], 1);
  }
  __syncthreads();
  for (int i = tid; i < NB; i += 512) {
    int c = hist[i];
    gb[i] = c ? atomicAdd(&gcursor[i], c) : 0;
  }
  __syncthreads();
  for (int i = tid; i < NB; i += 512) hist[i] = 0;
  __syncthreads();
  for (int i = tid; i < count; i += 512) {
    int b = (int)bkt[i];
    int idx = atomicAdd(&hist[b], 1);
    recs[gb[b] + idx] = rec[i];
  }
}

// --- 4. fused sort + gather + scale + matmul --------------------------------
// One block per bucket. BF16 path: 8 lanes (uint4 = 8 bf16 ch) x 8 edge
// slots, 64 edges in flight per wave.
template <bool USE_BF16>
__global__ __launch_bounds__(256) void sortgather_kernel(
    const float* __restrict__ x, const unsigned* __restrict__ xb,
    const unsigned* __restrict__ recs, const int* __restrict__ bbase,
    const float* __restrict__ norm, const float* __restrict__ W,
    float* __restrict__ out, int N) {
  __shared__ int cnt[BN];
  __shared__ int pre[BN];
  __shared__ int nstart[BN + 1];
  __shared__ int sorted[CAP];  // 24 KB
  int tid = threadIdx.x;
  int lane = tid & 63;
  int wave = tid >> 6;
  int b = blockIdx.x;
  int n0 = b * BN;
  int nn = N - n0; if (nn > BN) nn = BN;
  int beg = bbase[b], end = bbase[b + 1];
  int m = end - beg;

  float wreg[C];
#pragma unroll
  for (int k = 0; k < C; k++) wreg[k] = W[k * C + lane];

  // counting sort into LDS
  if (tid < BN) cnt[tid] = 0;
  __syncthreads();
  for (int r = beg + tid; r < end; r += 256)
    atomicAdd(&cnt[recs[r] & 127u], 1);
  __syncthreads();
  if (tid < BN) pre[tid] = cnt[tid];
  __syncthreads();
  for (int off = 1; off < BN; off <<= 1) {
    int v = 0, a = 0;
    if (tid < BN) { v = pre[tid]; a = (tid >= off) ? pre[tid - off] : 0; }
    __syncthreads();
    if (tid < BN) pre[tid] = v + a;
    __syncthreads();
  }
  if (tid < BN) {
    nstart[tid] = pre[tid] - cnt[tid];  // exclusive prefix
    cnt[tid] = pre[tid] - cnt[tid];     // bucket-local cursor
  }
  if (tid == 0) nstart[BN] = m;
  __syncthreads();
  bool fits = (m <= CAP);
  if (fits) {
    for (int r = beg + tid; r < end; r += 256) {
      unsigned rc = recs[r];
      int p = atomicAdd(&cnt[rc & 127u], 1);
      sorted[p] = (int)(rc >> 7);
    }
  }
  __syncthreads();

  int sub, grp;
  if (USE_BF16) { sub = lane & 7;  grp = lane >> 3; }
  else          { sub = lane & 15; grp = lane >> 4; }
  const float4* x4 = (const float4*)x;
  const uint4* xb4 = (const uint4*)xb;  // bf16 row = 8 uint4 (128 B)

  for (int i = wave; i < nn; i += 4) {
    int n = n0 + i;
    float acc[8];
    if (grp == 0) {  // exact fp32 self term
      if (USE_BF16) {
        float4 a = x4[n * 16 + sub * 2], bq = x4[n * 16 + sub * 2 + 1];
        acc[0] = a.x; acc[1] = a.y; acc[2] = a.z; acc[3] = a.w;
        acc[4] = bq.x; acc[5] = bq.y; acc[6] = bq.z; acc[7] = bq.w;
      } else {
        float4 a = x4[n * 16 + sub];
        acc[0] = a.x; acc[1] = a.y; acc[2] = a.z; acc[3] = a.w;
        acc[4] = acc[5] = acc[6] = acc[7] = 0.0f;
      }
    } else {
#pragma unroll
      for (int j = 0; j < 8; j++) acc[j] = 0.0f;
    }

    if (fits) {
      int gbeg = nstart[i], gend = nstart[i + 1];
      if (USE_BF16) {
        for (int e0 = gbeg; e0 < gend; e0 += 64) {
#pragma unroll
          for (int u = 0; u < 8; u++) {
            int e = e0 + 8 * u + grp;
            if (e < gend) {
              int s = sorted[e];
              uint4 v = xb4[s * 8 + sub];
              acc[0] += __uint_as_float(v.x << 16);
              acc[1] += __uint_as_float(v.x & 0xFFFF0000u);
              acc[2] += __uint_as_float(v.y << 16);
              acc[3] += __uint_as_float(v.y & 0xFFFF0000u);
              acc[4] += __uint_as_float(v.z << 16);
              acc[5] += __uint_as_float(v.z & 0xFFFF0000u);
              acc[6] += __uint_as_float(v.w << 16);
              acc[7] += __uint_as_float(v.w & 0xFFFF0000u);
            }
          }
        }
      } else {
        for (int e0 = gbeg; e0 < gend; e0 += 16) {
#pragma unroll
          for (int u = 0; u < 4; u++) {
            int e = e0 + 4 * u + grp;
            if (e < gend) {
              int s = sorted[e];
              float4 v = x4[s * 16 + sub];
              acc[0] += v.x; acc[1] += v.y; acc[2] += v.z; acc[3] += v.w;
            }
          }
        }
      }
    } else {  // overflow fallback (statistically unreachable): filtered scan
      for (int r0 = beg; r0 < end; r0 += (USE_BF16 ? 8 : 4)) {
        int e = r0 + grp;
        if (e < end) {
          unsigned rc = recs[e];
          if ((int)(rc & 127u) == i) {
            int s = (int)(rc >> 7);
            if (USE_BF16) {
              uint4 v = xb4[s * 8 + sub];
              acc[0] += __uint_as_float(v.x << 16);
              acc[1] += __uint_as_float(v.x & 0xFFFF0000u);
              acc[2] += __uint_as_float(v.y << 16);
              acc[3] += __uint_as_float(v.y & 0xFFFF0000u);
              acc[4] += __uint_as_float(v.z << 16);
              acc[5] += __uint_as_float(v.z & 0xFFFF0000u);
              acc[6] += __uint_as_float(v.w << 16);
              acc[7] += __uint_as_float(v.w & 0xFFFF0000u);
            } else {
              float4 v = x4[s * 16 + sub];
              acc[0] += v.x; acc[1] += v.y; acc[2] += v.z; acc[3] += v.w;
            }
          }
        }
      }
    }

    // reduce edge slots
    if (USE_BF16) {
#pragma unroll
      for (int j = 0; j < 8; j++) {
        acc[j] += __shfl_xor(acc[j], 8, 64);
        acc[j] += __shfl_xor(acc[j], 16, 64);
        acc[j] += __shfl_xor(acc[j], 32, 64);
      }
    } else {
#pragma unroll
      for (int j = 0; j < 4; j++) {
        acc[j] += __shfl_xor(acc[j], 16, 64);
        acc[j] += __shfl_xor(acc[j], 32, 64);
      }
    }

    float nv = norm[n];
    float o = 0.0f;
    if (USE_BF16) {
#pragma unroll
      for (int j = 0; j < 8; j++) acc[j] *= nv;
#pragma unroll
      for (int s = 0; s < 8; s++)
#pragma unroll
        for (int j = 0; j < 8; j++)
          o = fmaf(__shfl(acc[j], s, 64), wreg[8 * s + j], o);
    } else {
#pragma unroll
      for (int j = 0; j < 4; j++) acc[j] *= nv;
#pragma unroll
      for (int s = 0; s < 16; s++)
#pragma unroll
        for (int j = 0; j < 4; j++)
          o = fmaf(__shfl(acc[j], s, 64), wreg[4 * s + j], o);
    }
    out[n * C + lane] = o;
  }
}

extern "C" void kernel_launch(void* const* d_in, const int* in_sizes, int n_in,
                              void* d_out, int out_size, void* d_ws, size_t ws_size,
                              hipStream_t stream) {
  const float* x       = (const float*)d_in[0];
  const int*   sources = (const int*)d_in[1];
  const int*   targets = (const int*)d_in[2];
  const float* norm    = (const float*)d_in[3];
  const float* weight  = (const float*)d_in[4];
  float* out = (float*)d_out;

  int N = in_sizes[0] / C;     // 100000
  int E = in_sizes[1];         // 4000000
  int NB = (N + BN - 1) / BN;  // 782

  // ws (bf16): xb 12.8MB | bhist[NB] | bbase[NB+1] | cursor[NB] | recs[E] -> 28.8MB
  size_t xb_words = (size_t)N * C / 2;  // bf16 vals packed in unsigned words
  size_t meta_words = (size_t)3 * NB + 1 + (size_t)E;
  bool use_bf16 = ws_size >= (xb_words + meta_words) * 4;

  unsigned* xb; int* bhist;
  if (use_bf16) {
    xb = (unsigned*)d_ws;                 // 16B-aligned block first
    bhist = (int*)d_ws + xb_words;
  } else {
    xb = nullptr;
    bhist = (int*)d_ws;
  }
  int* bbase  = bhist + NB;
  int* cursor = bbase + (NB + 1);
  unsigned* recs = (unsigned*)(cursor + NB);

  hipMemsetAsync(bhist, 0, (size_t)NB * sizeof(int), stream);

  int hb = (E + CHUNK2 - 1) / CHUNK2;  // 489
  int total8 = N * C / 8;              // 800000
  int cvtBlocks = use_bf16 ? (total8 + 511) / 512 : 0;
  prep_kernel<<<hb + cvtBlocks, 512, 0, stream>>>(x, xb, targets, bhist, E, NB, hb, total8);
  bscan_kernel<<<1, 256, 0, stream>>>(bhist, bbase, cursor, NB);
  bin_kernel<<<hb, 512, 0, stream>>>(sources, targets, cursor, recs, E, NB);
  if (use_bf16) {
    sortgather_kernel<true><<<NB, 256, 0, stream>>>(x, xb, recs, bbase, norm, weight, out, N);
  } else {
    sortgather_kernel<false><<<NB, 256, 0, stream>>>(x, xb, recs, bbase, norm, weight, out, N);
  }
}